// Round 4
// baseline (762.142 us; speedup 1.0000x reference)
//
#include <hip/hip_runtime.h>

typedef unsigned short u16;
typedef short short8 __attribute__((ext_vector_type(8)));
typedef float f32x4 __attribute__((ext_vector_type(4)));

#define LOG2E 1.44269504088896340736f

__device__ __forceinline__ u16 f2bf(float f) {
  unsigned u = __builtin_bit_cast(unsigned, f);
  u += 0x7fffu + ((u >> 16) & 1u);
  return (u16)(u >> 16);
}

__device__ __forceinline__ unsigned cvt_pk_bf16(float lo, float hi) {
  unsigned r;
  asm("v_cvt_pk_bf16_f32 %0, %1, %2" : "=v"(r) : "v"(lo), "v"(hi));
  return r;
}

__device__ __forceinline__ short8 cat8(uint2 a, uint2 b) {
  int4 t;
  t.x = (int)a.x; t.y = (int)a.y; t.z = (int)b.x; t.w = (int)b.y;
  return __builtin_bit_cast(short8, t);
}

// ---------------- kernel 1: x fp32 -> bf16 ----------------
__global__ __launch_bounds__(256) void k_convert_x(const float* __restrict__ x,
                                                   u16* __restrict__ xb) {
  int i = blockIdx.x * 256 + threadIdx.x;
  float4 v = ((const float4*)x)[i];
  ushort4 o;
  o.x = f2bf(v.x); o.y = f2bf(v.y); o.z = f2bf(v.z); o.w = f2bf(v.w);
  ((ushort4*)xb)[i] = o;
}

// ---------------- kernel 2: WcatT [640][512] bf16 ----------------
__global__ __launch_bounds__(256) void k_wcat(const float* __restrict__ Wq,
                                              const float* __restrict__ Wk,
                                              const float* __restrict__ Wv,
                                              const float* __restrict__ Wo,
                                              u16* __restrict__ wcatT) {
  __shared__ float wo[512];
  int j = blockIdx.x;
  int t = threadIdx.x;
  if (j < 64) {
    for (int c = t; c < 512; c += 256)
      wcatT[j * 512 + c] = f2bf(Wq[c * 64 + j] * (0.125f * LOG2E));
  } else if (j < 128) {
    int jj = j - 64;
    for (int c = t; c < 512; c += 256)
      wcatT[j * 512 + c] = f2bf(Wk[c * 64 + jj]);
  } else {
    int jj = j - 128;
    for (int kk = t; kk < 512; kk += 256) wo[kk] = Wo[kk * 512 + jj];
    __syncthreads();
    for (int c = t; c < 512; c += 256) {
      const float4* wr = (const float4*)(Wv + c * 512);
      float acc = 0.f;
#pragma unroll 8
      for (int kk = 0; kk < 128; kk++) {
        float4 v = wr[kk];
        acc += v.x * wo[kk * 4 + 0] + v.y * wo[kk * 4 + 1] +
               v.z * wo[kk * 4 + 2] + v.w * wo[kk * 4 + 3];
      }
      wcatT[j * 512 + c] = f2bf(acc);
    }
  }
}

// ---------------- kernel 3: QKV' GEMM [16384,512]@[512,640] ----------------
__global__ __launch_bounds__(256) void k_qkv(const u16* __restrict__ xb,
                                             const u16* __restrict__ wcatT,
                                             u16* __restrict__ q,
                                             u16* __restrict__ k,
                                             u16* __restrict__ vT) {
  __shared__ u16 lds[17408];
  int tid = threadIdx.x;
  int w = tid >> 6, lane = tid & 63;
  int fr = lane & 15, fg = lane >> 4;
  int wm = w >> 1, wn = w & 1;
  int rowbase = blockIdx.y * 128;
  int jbase = blockIdx.x * 128;
  f32x4 acc[4][4] = {};

  for (int kb = 0; kb < 512; kb += 64) {
    __syncthreads();
#pragma unroll
    for (int n = 0; n < 4; n++) {
      int lin = n * 4096 + tid * 16;
      int row = lin >> 7;
      int src = (((lin >> 4) & 7) * 16) ^ ((row & 7) << 4);
      const char* ga = (const char*)(xb + (size_t)(rowbase + row) * 512 + kb) + src;
      __builtin_amdgcn_global_load_lds(
          (const __attribute__((address_space(1))) void*)ga,
          (__attribute__((address_space(3))) void*)((char*)lds + n * 4096 + (w << 10)),
          16, 0, 0);
    }
#pragma unroll
    for (int n = 0; n < 4; n++) {
      int lin = n * 4096 + tid * 16;
      int row = lin >> 7;
      int src = (((lin >> 4) & 7) * 16) ^ ((row & 7) << 4);
      const char* ga = (const char*)(wcatT + (size_t)(jbase + row) * 512 + kb) + src;
      __builtin_amdgcn_global_load_lds(
          (const __attribute__((address_space(1))) void*)ga,
          (__attribute__((address_space(3))) void*)((char*)lds + 16384 + n * 4096 + (w << 10)),
          16, 0, 0);
    }
    __syncthreads();
    short8 af[4][2], bfr[4][2];
#pragma unroll
    for (int mt = 0; mt < 4; mt++)
#pragma unroll
      for (int ks = 0; ks < 2; ks++) {
        int row = wm * 64 + mt * 16 + fr;
        int off = row * 128 + ((ks * 64 + fg * 16) ^ ((row & 7) << 4));
        af[mt][ks] = *(const short8*)((const char*)lds + off);
      }
#pragma unroll
    for (int nt = 0; nt < 4; nt++)
#pragma unroll
      for (int ks = 0; ks < 2; ks++) {
        int j = wn * 64 + nt * 16 + fr;
        int off = 16384 + j * 128 + ((ks * 64 + fg * 16) ^ ((j & 7) << 4));
        bfr[nt][ks] = *(const short8*)((const char*)lds + off);
      }
#pragma unroll
    for (int ks = 0; ks < 2; ks++)
#pragma unroll
      for (int mt = 0; mt < 4; mt++)
#pragma unroll
        for (int nt = 0; nt < 4; nt++)
          acc[mt][nt] = __builtin_amdgcn_mfma_f32_16x16x32_bf16(
              af[mt][ks], bfr[nt][ks], acc[mt][nt], 0, 0, 0);
  }

  if (jbase < 128) {
    int r0 = rowbase + wm * 64, j0 = jbase + wn * 64;
#pragma unroll
    for (int mt = 0; mt < 4; mt++)
#pragma unroll
      for (int nt = 0; nt < 4; nt++) {
        int j16 = j0 + nt * 16 + fr;
#pragma unroll
        for (int ii = 0; ii < 4; ii++) {
          int rg = r0 + mt * 16 + fg * 4 + ii;
          u16 v = f2bf(acc[mt][nt][ii]);
          if (j16 < 64) q[rg * 64 + j16] = v;
          else          k[rg * 64 + (j16 - 64)] = v;
        }
      }
  } else {
    __syncthreads();
#pragma unroll
    for (int mt = 0; mt < 4; mt++)
#pragma unroll
      for (int nt = 0; nt < 4; nt++) {
        int lc = wn * 64 + nt * 16 + fr;
#pragma unroll
        for (int ii = 0; ii < 4; ii++) {
          int ln = wm * 64 + mt * 16 + fg * 4 + ii;
          lds[lc * 136 + ln] = f2bf(acc[mt][nt][ii]);
        }
      }
    __syncthreads();
    int batch = rowbase >> 12;
    int nb = rowbase & 4095;
    int seg = tid & 15, lcq = tid >> 4;
#pragma unroll
    for (int it = 0; it < 8; it++) {
      int lc = it * 16 + lcq;
      uint4 val = *(const uint4*)&lds[lc * 136 + seg * 8];
      int cg = (jbase - 128) + lc;
      *(uint4*)(vT + (((size_t)(batch * 512 + cg)) << 12) + nb + seg * 8) = val;
    }
  }
}

// ---------------- kernel 4: barrier-free flash attention + epilogue ----------------
// 512 WGs of 256 thr (4 waves). WG owns 32 q-rows; every wave computes S for all
// 32 rows (swapped QK^T: lane fr = q-row), softmax fully in-register, PV on a
// private 128-col slice of O. No LDS, no __syncthreads in the whole kernel.
__global__ __launch_bounds__(256, 3) void k_attn(const u16* __restrict__ q,
                                                 const u16* __restrict__ k,
                                                 const u16* __restrict__ vT,
                                                 const float* __restrict__ x,
                                                 const float* __restrict__ gamma_p,
                                                 float* __restrict__ out) {
  int bi = blockIdx.x;
  int xcd = bi & 7;
  int b = xcd >> 1;
  int qt = ((bi >> 3) << 1) | (xcd & 1);   // bijective, 2 XCDs per batch
  int qbase = qt * 32;

  int tid = threadIdx.x;
  int w = tid >> 6, lane = tid & 63;
  int fr = lane & 15, fg = lane >> 4;
  int c0 = w * 128;

  // Q fragments: qa[rt][sl], B-operand layout (lane fr = q-row)
  short8 qa[2][2];
#pragma unroll
  for (int rt = 0; rt < 2; rt++) {
    const u16* qp = q + ((size_t)((b << 12) + qbase + rt * 16 + fr)) * 64 + fg * 8;
    qa[rt][0] = *(const short8*)qp;
    qa[rt][1] = *(const short8*)(qp + 32);
  }

  f32x4 o[2][8] = {};
  float mR[2] = {-1e30f, -1e30f};
  float lR[2] = {0.f, 0.f};

  // K base: A-operand (lane fr = key row within 16-tile), fg*16 bytes = r-slice
  const char* kbase = (const char*)(k + ((size_t)b << 18)) + fr * 128 + fg * 16;
  // V^T bases per c-tile nt: row = b*512 + c0 + nt*16 + fr; +8*fg bytes = key off 4*fg
  const char* vb[8];
#pragma unroll
  for (int nt = 0; nt < 8; nt++)
    vb[nt] = (const char*)vT + (((size_t)(b * 512 + c0 + nt * 16 + fr)) << 13) + fg * 8;

  for (int kt = 0; kt < 64; kt++) {
    const char* kp = kbase + kt * 8192;
    f32x4 s[2][4] = {};
    // ---- QK^T (swapped): 16 MFMAs, K loaded in 2 halves ----
    {
      short8 kc[2][2];
      kc[0][0] = *(const short8*)(kp);
      kc[0][1] = *(const short8*)(kp + 64);
      kc[1][0] = *(const short8*)(kp + 2048);
      kc[1][1] = *(const short8*)(kp + 2112);
#pragma unroll
      for (int sl = 0; sl < 2; sl++)
#pragma unroll
        for (int kb = 0; kb < 2; kb++)
#pragma unroll
          for (int rt = 0; rt < 2; rt++)
            s[rt][kb] = __builtin_amdgcn_mfma_f32_16x16x32_bf16(kc[kb][sl], qa[rt][sl], s[rt][kb], 0, 0, 0);
    }
    {
      short8 kc[2][2];
      kc[0][0] = *(const short8*)(kp + 4096);
      kc[0][1] = *(const short8*)(kp + 4160);
      kc[1][0] = *(const short8*)(kp + 6144);
      kc[1][1] = *(const short8*)(kp + 6208);
#pragma unroll
      for (int sl = 0; sl < 2; sl++)
#pragma unroll
        for (int kb = 0; kb < 2; kb++)
#pragma unroll
          for (int rt = 0; rt < 2; rt++)
            s[rt][kb + 2] = __builtin_amdgcn_mfma_f32_16x16x32_bf16(kc[kb][sl], qa[rt][sl], s[rt][kb + 2], 0, 0, 0);
    }
    // ---- V group A loads (nt 0..3), latency hides under softmax ----
    uint2 vA[4][2][2];
#pragma unroll
    for (int nt = 0; nt < 4; nt++)
#pragma unroll
      for (int ks = 0; ks < 2; ks++)
#pragma unroll
        for (int h = 0; h < 2; h++)
          vA[nt][ks][h] = *(const uint2*)(vb[nt] + kt * 128 + ks * 64 + h * 32);

    // ---- in-register online softmax (per rt); lane fr = q-row ----
    short8 pk[2][2];
#pragma unroll
    for (int rt = 0; rt < 2; rt++) {
      float tm = s[rt][0][0];
#pragma unroll
      for (int kb = 0; kb < 4; kb++)
#pragma unroll
        for (int ii = 0; ii < 4; ii++) tm = fmaxf(tm, s[rt][kb][ii]);
      tm = fmaxf(tm, __shfl_xor(tm, 16));
      tm = fmaxf(tm, __shfl_xor(tm, 32));
      float m = mR[rt];
      if (__builtin_expect(__any(tm > m + 8.0f), 0)) {   // defer-max THR=8
        float mn = fmaxf(m, tm);
        float cr = exp2f(m - mn);                         // cr==1 for lanes not needing
#pragma unroll
        for (int nt = 0; nt < 8; nt++)
#pragma unroll
          for (int ii = 0; ii < 4; ii++) o[rt][nt][ii] *= cr;
        lR[rt] *= cr;
        m = mn;
        mR[rt] = mn;
      }
      float p[4][4];
      float ts = 0.f;
#pragma unroll
      for (int kb = 0; kb < 4; kb++)
#pragma unroll
        for (int ii = 0; ii < 4; ii++) {
          p[kb][ii] = exp2f(s[rt][kb][ii] - m);
          ts += p[kb][ii];
        }
      ts += __shfl_xor(ts, 16);
      ts += __shfl_xor(ts, 32);
      lR[rt] += ts;
      // pack to PV B-fragments (pure in-lane, pi-mapped k order)
#pragma unroll
      for (int ks = 0; ks < 2; ks++) {
        int4 pi;
        pi.x = (int)cvt_pk_bf16(p[2 * ks][0], p[2 * ks][1]);
        pi.y = (int)cvt_pk_bf16(p[2 * ks][2], p[2 * ks][3]);
        pi.z = (int)cvt_pk_bf16(p[2 * ks + 1][0], p[2 * ks + 1][1]);
        pi.w = (int)cvt_pk_bf16(p[2 * ks + 1][2], p[2 * ks + 1][3]);
        pk[rt][ks] = __builtin_bit_cast(short8, pi);
      }
    }
    // ---- V group B loads (nt 4..7) ----
    uint2 vB[4][2][2];
#pragma unroll
    for (int nt = 0; nt < 4; nt++)
#pragma unroll
      for (int ks = 0; ks < 2; ks++)
#pragma unroll
        for (int h = 0; h < 2; h++)
          vB[nt][ks][h] = *(const uint2*)(vb[nt + 4] + kt * 128 + ks * 64 + h * 32);
    // ---- PV: 32 MFMAs ----
#pragma unroll
    for (int nt = 0; nt < 4; nt++) {
      short8 va0 = cat8(vA[nt][0][0], vA[nt][0][1]);
      short8 va1 = cat8(vA[nt][1][0], vA[nt][1][1]);
      o[0][nt] = __builtin_amdgcn_mfma_f32_16x16x32_bf16(va0, pk[0][0], o[0][nt], 0, 0, 0);
      o[0][nt] = __builtin_amdgcn_mfma_f32_16x16x32_bf16(va1, pk[0][1], o[0][nt], 0, 0, 0);
      o[1][nt] = __builtin_amdgcn_mfma_f32_16x16x32_bf16(va0, pk[1][0], o[1][nt], 0, 0, 0);
      o[1][nt] = __builtin_amdgcn_mfma_f32_16x16x32_bf16(va1, pk[1][1], o[1][nt], 0, 0, 0);
    }
#pragma unroll
    for (int nt = 0; nt < 4; nt++) {
      short8 va0 = cat8(vB[nt][0][0], vB[nt][0][1]);
      short8 va1 = cat8(vB[nt][1][0], vB[nt][1][1]);
      o[0][nt + 4] = __builtin_amdgcn_mfma_f32_16x16x32_bf16(va0, pk[0][0], o[0][nt + 4], 0, 0, 0);
      o[0][nt + 4] = __builtin_amdgcn_mfma_f32_16x16x32_bf16(va1, pk[0][1], o[0][nt + 4], 0, 0, 0);
      o[1][nt + 4] = __builtin_amdgcn_mfma_f32_16x16x32_bf16(va0, pk[1][0], o[1][nt + 4], 0, 0, 0);
      o[1][nt + 4] = __builtin_amdgcn_mfma_f32_16x16x32_bf16(va1, pk[1][1], o[1][nt + 4], 0, 0, 0);
    }
  }

  // ---- epilogue: out = gamma * O/l + x ; lane fr = row, o[rt][nt][ii] = col c0+16nt+4fg+ii
  float g = gamma_p[0];
#pragma unroll
  for (int rt = 0; rt < 2; rt++) {
    float il = 1.0f / lR[rt];
    size_t row = (size_t)((b << 12) + qbase + rt * 16 + fr);
#pragma unroll
    for (int nt = 0; nt < 8; nt++) {
      size_t idx = row * 512 + c0 + nt * 16 + fg * 4;
      float4 xo = *(const float4*)(x + idx);
      float4 r;
      r.x = g * o[rt][nt][0] * il + xo.x;
      r.y = g * o[rt][nt][1] * il + xo.y;
      r.z = g * o[rt][nt][2] * il + xo.z;
      r.w = g * o[rt][nt][3] * il + xo.w;
      *(float4*)(out + idx) = r;
    }
  }
}

extern "C" void kernel_launch(void* const* d_in, const int* in_sizes, int n_in,
                              void* d_out, int out_size, void* d_ws, size_t ws_size,
                              hipStream_t stream) {
  const float* x  = (const float*)d_in[0];
  const float* Wq = (const float*)d_in[1];
  const float* Wk = (const float*)d_in[2];
  const float* Wv = (const float*)d_in[3];
  const float* Wo = (const float*)d_in[4];
  const float* gm = (const float*)d_in[5];
  float* out = (float*)d_out;

  char* ws = (char*)d_ws;
  u16* xb    = (u16*)(ws);
  u16* wcatT = (u16*)(ws + 16777216);
  u16* q     = (u16*)(ws + 17432576);
  u16* k     = (u16*)(ws + 19529728);
  u16* vT    = (u16*)(ws + 21626880);

  hipLaunchKernelGGL(k_convert_x, dim3(8192), dim3(256), 0, stream, x, xb);
  hipLaunchKernelGGL(k_wcat, dim3(640), dim3(256), 0, stream, Wq, Wk, Wv, Wo, wcatT);
  hipLaunchKernelGGL(k_qkv, dim3(5, 128), dim3(256), 0, stream, xb, wcatT, q, k, vT);
  hipLaunchKernelGGL(k_attn, dim3(512), dim3(256), 0, stream, q, k, vT, x, gm, out);
}

// Round 5
// 359.699 us; speedup vs baseline: 2.1188x; 2.1188x over previous
//
#include <hip/hip_runtime.h>

typedef unsigned short u16;
typedef short short8 __attribute__((ext_vector_type(8)));
typedef float f32x4 __attribute__((ext_vector_type(4)));

#define LOG2E 1.44269504088896340736f

__device__ __forceinline__ u16 f2bf(float f) {
  unsigned u = __builtin_bit_cast(unsigned, f);
  u += 0x7fffu + ((u >> 16) & 1u);
  return (u16)(u >> 16);
}

__device__ __forceinline__ unsigned cvt_pk_bf16(float lo, float hi) {
  unsigned r;
  asm("v_cvt_pk_bf16_f32 %0, %1, %2" : "=v"(r) : "v"(lo), "v"(hi));
  return r;
}

// ---------------- kernel 1: x fp32 -> bf16 ----------------
__global__ __launch_bounds__(256) void k_convert_x(const float* __restrict__ x,
                                                   u16* __restrict__ xb) {
  int i = blockIdx.x * 256 + threadIdx.x;
  float4 v = ((const float4*)x)[i];
  ushort4 o;
  o.x = f2bf(v.x); o.y = f2bf(v.y); o.z = f2bf(v.z); o.w = f2bf(v.w);
  ((ushort4*)xb)[i] = o;
}

// ---------------- kernel 2: WcatT [640][512] bf16 ----------------
// blocks 0-7: rows 0..127 (Wq^T*scale, Wk^T). blocks 8-71: (Wv@Wo)^T, 8 cols each.
__global__ __launch_bounds__(256) void k_wcat(const float* __restrict__ Wq,
                                              const float* __restrict__ Wk,
                                              const float* __restrict__ Wv,
                                              const float* __restrict__ Wo,
                                              u16* __restrict__ wcatT) {
  __shared__ float wo8T[8 * 512];
  int bid = blockIdx.x, t = threadIdx.x;
  if (bid < 8) {
    for (int i = t; i < 8192; i += 256) {
      int j = bid * 16 + (i >> 9);
      int c = i & 511;
      float v = (j < 64) ? Wq[c * 64 + j] * (0.125f * LOG2E) : Wk[c * 64 + (j - 64)];
      wcatT[j * 512 + c] = f2bf(v);
    }
  } else {
    int j0 = (bid - 8) * 8;
    for (int i = t; i < 4096; i += 256) {
      int jj = i >> 9, kk = i & 511;
      wo8T[jj * 512 + kk] = Wo[kk * 512 + j0 + jj];
    }
    __syncthreads();
    for (int c = t; c < 512; c += 256) {
      const float4* wr = (const float4*)(Wv + c * 512);
      float acc[8] = {};
      for (int kk = 0; kk < 128; kk++) {
        float4 v = wr[kk];
#pragma unroll
        for (int jj = 0; jj < 8; jj++) {
          float4 wa = *(const float4*)&wo8T[jj * 512 + kk * 4];
          acc[jj] += v.x * wa.x + v.y * wa.y + v.z * wa.z + v.w * wa.w;
        }
      }
#pragma unroll
      for (int jj = 0; jj < 8; jj++)
        wcatT[(128 + j0 + jj) * 512 + c] = f2bf(acc[jj]);
    }
  }
}

// ---------------- kernel 3: QKV' GEMM [16384,512]@[512,640] ----------------
// q  [16384][64] bf16 (row-major)
// kf fragment layout: u16 idx = ((((b*64+kt)*4+kb)*2+sl)*16+fr)*32 + fgk*8 + e
//    (key n: kt=n>>6, kb=(n>>4)&3, fr=n&15; d: sl=d>>5, fgk=(d&31)>>3, e=d&7)
// vf fragment layout: u16 idx = ((((b*64+kt)*32+ct)*2+ks)*16+fr)*32 + fg*8 + h*4 + e
//    (key n: kt=n>>6, ks=(n>>5)&1, h=(n>>4)&1, fg=(n&15)>>2, e=n&3; col c: ct=c>>4, fr=c&15)
__global__ __launch_bounds__(256) void k_qkv(const u16* __restrict__ xb,
                                             const u16* __restrict__ wcatT,
                                             u16* __restrict__ q,
                                             u16* __restrict__ kf,
                                             u16* __restrict__ vf) {
  __shared__ u16 lds[16384];
  int tid = threadIdx.x;
  int w = tid >> 6, lane = tid & 63;
  int fr = lane & 15, fg = lane >> 4;
  int wm = w >> 1, wn = w & 1;
  int rowbase = blockIdx.y * 128;
  int jbase = blockIdx.x * 128;
  f32x4 acc[4][4] = {};

  for (int kb = 0; kb < 512; kb += 64) {
    __syncthreads();
#pragma unroll
    for (int n = 0; n < 4; n++) {
      int lin = n * 4096 + tid * 16;
      int row = lin >> 7;
      int src = (((lin >> 4) & 7) * 16) ^ ((row & 7) << 4);
      const char* ga = (const char*)(xb + (size_t)(rowbase + row) * 512 + kb) + src;
      __builtin_amdgcn_global_load_lds(
          (const __attribute__((address_space(1))) void*)ga,
          (__attribute__((address_space(3))) void*)((char*)lds + n * 4096 + (w << 10)),
          16, 0, 0);
    }
#pragma unroll
    for (int n = 0; n < 4; n++) {
      int lin = n * 4096 + tid * 16;
      int row = lin >> 7;
      int src = (((lin >> 4) & 7) * 16) ^ ((row & 7) << 4);
      const char* ga = (const char*)(wcatT + (size_t)(jbase + row) * 512 + kb) + src;
      __builtin_amdgcn_global_load_lds(
          (const __attribute__((address_space(1))) void*)ga,
          (__attribute__((address_space(3))) void*)((char*)lds + 16384 + n * 4096 + (w << 10)),
          16, 0, 0);
    }
    __syncthreads();
    short8 af[4][2], bfr[4][2];
#pragma unroll
    for (int mt = 0; mt < 4; mt++)
#pragma unroll
      for (int ks = 0; ks < 2; ks++) {
        int row = wm * 64 + mt * 16 + fr;
        int off = row * 128 + ((ks * 64 + fg * 16) ^ ((row & 7) << 4));
        af[mt][ks] = *(const short8*)((const char*)lds + off);
      }
#pragma unroll
    for (int nt = 0; nt < 4; nt++)
#pragma unroll
      for (int ks = 0; ks < 2; ks++) {
        int j = wn * 64 + nt * 16 + fr;
        int off = 16384 + j * 128 + ((ks * 64 + fg * 16) ^ ((j & 7) << 4));
        bfr[nt][ks] = *(const short8*)((const char*)lds + off);
      }
#pragma unroll
    for (int ks = 0; ks < 2; ks++)
#pragma unroll
      for (int mt = 0; mt < 4; mt++)
#pragma unroll
        for (int nt = 0; nt < 4; nt++)
          acc[mt][nt] = __builtin_amdgcn_mfma_f32_16x16x32_bf16(
              af[mt][ks], bfr[nt][ks], acc[mt][nt], 0, 0, 0);
  }

  if (jbase < 128) {
    int r0 = rowbase + wm * 64, j0 = jbase + wn * 64;
    if (wn == 0) {
      // q rows: [rg][64]
#pragma unroll
      for (int mt = 0; mt < 4; mt++)
#pragma unroll
        for (int nt = 0; nt < 4; nt++) {
          int j16 = j0 + nt * 16 + fr;
#pragma unroll
          for (int ii = 0; ii < 4; ii++) {
            int rg = r0 + mt * 16 + fg * 4 + ii;
            q[rg * 64 + j16] = f2bf(acc[mt][nt][ii]);
          }
        }
    } else {
      // kf fragment stores
      int bb = r0 >> 12;
      int kt = (r0 & 4095) >> 6;
#pragma unroll
      for (int mt = 0; mt < 4; mt++)
#pragma unroll
        for (int nt = 0; nt < 4; nt++) {
          int dd = nt * 16 + fr;
          int sl = dd >> 5, fgk = (dd & 31) >> 3, e = dd & 7;
#pragma unroll
          for (int ii = 0; ii < 4; ii++) {
            size_t idx = ((((size_t)((bb * 64 + kt) * 4 + mt) * 2 + sl) * 16 +
                           (fg * 4 + ii)) * 32) + fgk * 8 + e;
            kf[idx] = f2bf(acc[mt][nt][ii]);
          }
        }
    }
  } else {
    // vf fragment stores: 16B per (mt-pair, nt), fully coalesced
    int bb = rowbase >> 12;
    int ktb = ((rowbase & 4095) >> 6) + wm;
    int cbase = (jbase - 128) + wn * 64;
#pragma unroll
    for (int nt = 0; nt < 4; nt++) {
      int c = cbase + nt * 16 + fr;
      int ct = c >> 4;
#pragma unroll
      for (int mp = 0; mp < 2; mp++) {  // mt pair (2mp, 2mp+1); ks = mp
        uint4 u;
        u.x = cvt_pk_bf16(acc[2 * mp][nt][0], acc[2 * mp][nt][1]);
        u.y = cvt_pk_bf16(acc[2 * mp][nt][2], acc[2 * mp][nt][3]);
        u.z = cvt_pk_bf16(acc[2 * mp + 1][nt][0], acc[2 * mp + 1][nt][1]);
        u.w = cvt_pk_bf16(acc[2 * mp + 1][nt][2], acc[2 * mp + 1][nt][3]);
        size_t off16 = (((size_t)((bb * 64 + ktb) * 32 + ct) * 2 + mp) * 16 + fr) * 4 + fg;
        *(uint4*)((char*)vf + off16 * 16) = u;
      }
    }
  }
}

// ---------------- kernel 4: barrier-free flash attention, coalesced frags ----------------
__global__ __launch_bounds__(256, 2) void k_attn(const u16* __restrict__ q,
                                                 const u16* __restrict__ kf,
                                                 const u16* __restrict__ vf,
                                                 const float* __restrict__ x,
                                                 const float* __restrict__ gamma_p,
                                                 float* __restrict__ out) {
  int bi = blockIdx.x;
  int xcd = bi & 7, b = xcd >> 1;
  int qt = ((bi >> 3) << 1) | (xcd & 1);  // bijective, 2 XCDs per batch
  int qbase = qt * 32;

  int tid = threadIdx.x;
  int w = tid >> 6, lane = tid & 63;
  int fr = lane & 15, fg = lane >> 4;
  int c0 = w * 128;

  short8 qa[2][2];
#pragma unroll
  for (int rt = 0; rt < 2; rt++) {
    const u16* qp = q + ((size_t)((b << 12) + qbase + rt * 16 + fr)) * 64 + fg * 8;
    qa[rt][0] = *(const short8*)qp;
    qa[rt][1] = *(const short8*)(qp + 32);
  }

  f32x4 o[2][8] = {};
  float mR[2] = {-1e30f, -1e30f};
  float lR[2] = {0.f, 0.f};
  const f32x4 zero4 = {};

  const char* kfb = (const char*)(kf + ((size_t)b << 18)) + fr * 64 + fg * 16;
  const char* vfb = (const char*)(vf + ((size_t)b << 21)) + (w * 8) * 2048 + fr * 64 + fg * 16;

#define LOADKC(DST, T)                                                       \
  {                                                                          \
    const char* kp_ = kfb + (size_t)(T) * 8192;                              \
    _Pragma("unroll") for (int kb_ = 0; kb_ < 4; kb_++)                      \
        _Pragma("unroll") for (int sl_ = 0; sl_ < 2; sl_++)                  \
            DST[kb_][sl_] = *(const short8*)(kp_ + kb_ * 2048 + sl_ * 1024); \
  }

#define BODY(T, KU, KP)                                                                   \
  {                                                                                       \
    const char* vp = vfb + (size_t)(T) * 65536;                                           \
    f32x4 s[2][4];                                                                        \
    _Pragma("unroll") for (int rt = 0; rt < 2; rt++)                                      \
        _Pragma("unroll") for (int kb = 0; kb < 4; kb++)                                  \
            s[rt][kb] = __builtin_amdgcn_mfma_f32_16x16x32_bf16(KU[kb][0], qa[rt][0],     \
                                                                zero4, 0, 0, 0);          \
    _Pragma("unroll") for (int rt = 0; rt < 2; rt++)                                      \
        _Pragma("unroll") for (int kb = 0; kb < 4; kb++)                                  \
            s[rt][kb] = __builtin_amdgcn_mfma_f32_16x16x32_bf16(KU[kb][1], qa[rt][1],     \
                                                                s[rt][kb], 0, 0, 0);      \
    LOADKC(KP, ((T) + 1) & 63);                                                           \
    short8 vaA[4][2];                                                                     \
    _Pragma("unroll") for (int nt = 0; nt < 4; nt++)                                      \
        _Pragma("unroll") for (int ks = 0; ks < 2; ks++)                                  \
            vaA[nt][ks] = *(const short8*)(vp + nt * 2048 + ks * 1024);                   \
    short8 pk[2][2];                                                                      \
    _Pragma("unroll") for (int rt = 0; rt < 2; rt++) {                                    \
      float tm = s[rt][0][0];                                                             \
      _Pragma("unroll") for (int kb = 0; kb < 4; kb++)                                    \
          _Pragma("unroll") for (int ii = 0; ii < 4; ii++)                                \
              tm = fmaxf(tm, s[rt][kb][ii]);                                              \
      tm = fmaxf(tm, __shfl_xor(tm, 16));                                                 \
      tm = fmaxf(tm, __shfl_xor(tm, 32));                                                 \
      float m = mR[rt];                                                                   \
      if (__builtin_expect(__any(tm > m + 8.0f), 0)) {                                    \
        float mn = fmaxf(m, tm);                                                          \
        float cr = exp2f(m - mn);                                                         \
        _Pragma("unroll") for (int nt = 0; nt < 8; nt++)                                  \
            _Pragma("unroll") for (int ii = 0; ii < 4; ii++) o[rt][nt][ii] *= cr;         \
        lR[rt] *= cr;                                                                     \
        m = mn;                                                                           \
        mR[rt] = mn;                                                                      \
      }                                                                                   \
      float p[4][4];                                                                      \
      float ts = 0.f;                                                                     \
      _Pragma("unroll") for (int kb = 0; kb < 4; kb++)                                    \
          _Pragma("unroll") for (int ii = 0; ii < 4; ii++) {                              \
        p[kb][ii] = exp2f(s[rt][kb][ii] - m);                                             \
        ts += p[kb][ii];                                                                  \
      }                                                                                   \
      ts += __shfl_xor(ts, 16);                                                           \
      ts += __shfl_xor(ts, 32);                                                           \
      lR[rt] += ts;                                                                       \
      _Pragma("unroll") for (int ks = 0; ks < 2; ks++) {                                  \
        int4 pi;                                                                          \
        pi.x = (int)cvt_pk_bf16(p[2 * ks][0], p[2 * ks][1]);                              \
        pi.y = (int)cvt_pk_bf16(p[2 * ks][2], p[2 * ks][3]);                              \
        pi.z = (int)cvt_pk_bf16(p[2 * ks + 1][0], p[2 * ks + 1][1]);                      \
        pi.w = (int)cvt_pk_bf16(p[2 * ks + 1][2], p[2 * ks + 1][3]);                      \
        pk[rt][ks] = __builtin_bit_cast(short8, pi);                                      \
      }                                                                                   \
    }                                                                                     \
    short8 vaB[4][2];                                                                     \
    _Pragma("unroll") for (int nt = 0; nt < 4; nt++)                                      \
        _Pragma("unroll") for (int ks = 0; ks < 2; ks++)                                  \
            vaB[nt][ks] = *(const short8*)(vp + (nt + 4) * 2048 + ks * 1024);             \
    __builtin_amdgcn_s_setprio(1);                                                        \
    _Pragma("unroll") for (int nt = 0; nt < 4; nt++) {                                    \
      o[0][nt] = __builtin_amdgcn_mfma_f32_16x16x32_bf16(vaA[nt][0], pk[0][0], o[0][nt], 0, 0, 0); \
      o[0][nt] = __builtin_amdgcn_mfma_f32_16x16x32_bf16(vaA[nt][1], pk[0][1], o[0][nt], 0, 0, 0); \
      o[1][nt] = __builtin_amdgcn_mfma_f32_16x16x32_bf16(vaA[nt][0], pk[1][0], o[1][nt], 0, 0, 0); \
      o[1][nt] = __builtin_amdgcn_mfma_f32_16x16x32_bf16(vaA[nt][1], pk[1][1], o[1][nt], 0, 0, 0); \
    }                                                                                     \
    _Pragma("unroll") for (int nt = 0; nt < 4; nt++) {                                    \
      o[0][nt + 4] = __builtin_amdgcn_mfma_f32_16x16x32_bf16(vaB[nt][0], pk[0][0], o[0][nt + 4], 0, 0, 0); \
      o[0][nt + 4] = __builtin_amdgcn_mfma_f32_16x16x32_bf16(vaB[nt][1], pk[0][1], o[0][nt + 4], 0, 0, 0); \
      o[1][nt + 4] = __builtin_amdgcn_mfma_f32_16x16x32_bf16(vaB[nt][0], pk[1][0], o[1][nt + 4], 0, 0, 0); \
      o[1][nt + 4] = __builtin_amdgcn_mfma_f32_16x16x32_bf16(vaB[nt][1], pk[1][1], o[1][nt + 4], 0, 0, 0); \
    }                                                                                     \
    __builtin_amdgcn_s_setprio(0);                                                        \
  }

  short8 kcA[4][2], kcB[4][2];
  LOADKC(kcA, 0);
  for (int kt = 0; kt < 64; kt += 2) {
    BODY(kt, kcA, kcB);
    BODY(kt + 1, kcB, kcA);
  }

  // epilogue: out = gamma * O/l + x
  float g = gamma_p[0];
#pragma unroll
  for (int rt = 0; rt < 2; rt++) {
    float il = 1.0f / lR[rt];
    size_t row = (size_t)((b << 12) + qbase + rt * 16 + fr);
#pragma unroll
    for (int nt = 0; nt < 8; nt++) {
      size_t idx = row * 512 + c0 + nt * 16 + fg * 4;
      float4 xo = *(const float4*)(x + idx);
      float4 r;
      r.x = g * o[rt][nt][0] * il + xo.x;
      r.y = g * o[rt][nt][1] * il + xo.y;
      r.z = g * o[rt][nt][2] * il + xo.z;
      r.w = g * o[rt][nt][3] * il + xo.w;
      *(float4*)(out + idx) = r;
    }
  }
#undef BODY
#undef LOADKC
}

extern "C" void kernel_launch(void* const* d_in, const int* in_sizes, int n_in,
                              void* d_out, int out_size, void* d_ws, size_t ws_size,
                              hipStream_t stream) {
  const float* x  = (const float*)d_in[0];
  const float* Wq = (const float*)d_in[1];
  const float* Wk = (const float*)d_in[2];
  const float* Wv = (const float*)d_in[3];
  const float* Wo = (const float*)d_in[4];
  const float* gm = (const float*)d_in[5];
  float* out = (float*)d_out;

  char* ws = (char*)d_ws;
  u16* xb    = (u16*)(ws);
  u16* wcatT = (u16*)(ws + 16777216);
  u16* q     = (u16*)(ws + 17432576);
  u16* kf    = (u16*)(ws + 19529728);
  u16* vf    = (u16*)(ws + 21626880);

  hipLaunchKernelGGL(k_convert_x, dim3(8192), dim3(256), 0, stream, x, xb);
  hipLaunchKernelGGL(k_wcat, dim3(72), dim3(256), 0, stream, Wq, Wk, Wv, Wo, wcatT);
  hipLaunchKernelGGL(k_qkv, dim3(5, 128), dim3(256), 0, stream, xb, wcatT, q, kf, vf);
  hipLaunchKernelGGL(k_attn, dim3(512), dim3(256), 0, stream, q, kf, vf, x, gm, out);
}